// Round 8
// baseline (119.008 us; speedup 1.0000x reference)
//
#include <hip/hip_runtime.h>
#include <math.h>
#include <float.h>

// Problem constants (B=16, T=4096, D=64, K=1024)
#define NROWS    65536
#define DD       64
#define KK       1024
#define LOSS_OFF 4194304
#define IDX_OFF  4194305
#define RPB      64           // rows per block (4 waves x 16 rows)
#define MAXC     32           // candidate list capacity per row (r3..r7-verified)

typedef short  short8 __attribute__((ext_vector_type(8)));   // 8 bf16
typedef float  f32x4  __attribute__((ext_vector_type(4)));

// float -> bf16 bits, RNE. Filter-side only.
__device__ __forceinline__ unsigned short bf16rne(float x) {
    unsigned int u = __float_as_uint(x);
    return (unsigned short)((u + 0x7fffu + ((u >> 16) & 1u)) >> 16);
}

// numpy strided accumulator r_j for n=64 pairwise sum (r6/r7-verified).
__device__ __forceinline__ float np_acc8(const float* p, int j) {
#pragma clang fp contract(off)
    float r = 0.f;
#pragma unroll
    for (int i = 0; i < 8; ++i) {
        const float v = p[8 * i + j];
        r += v * v;
    }
    return r;
}

// Prep (r5 layout, verified): norms bit-exact + fragment-ordered ebf:
// tile g stored as [1024B b0 frags in lane order][1024B b1 frags].
__global__ void vq_prep(const float* __restrict__ emb,
                        float* __restrict__ bn,
                        unsigned short* __restrict__ ebf) {
#pragma clang fp contract(off)
    const int gtid = blockIdx.x * 256 + threadIdx.x;   // 8192 threads
    const int code = gtid >> 3;
    const int j    = gtid & 7;
    const float* ep = emb + (size_t)code * DD;
    float r = 0.f;
#pragma unroll
    for (int i = 0; i < 8; ++i) {
        const float v = ep[8 * i + j];
        r += v * v;
    }
    const float s1 = r  + __shfl_xor(r,  1, 64);
    const float s2 = s1 + __shfl_xor(s1, 2, 64);
    const float s3 = s2 + __shfl_xor(s2, 4, 64);
    if (j == 0) bn[code] = s3;

    const float* cp = emb + (size_t)gtid * 8;
    const float4 u0 = *reinterpret_cast<const float4*>(cp);
    const float4 u1 = *reinterpret_cast<const float4*>(cp + 4);
    short8 s;
    s[0] = (short)bf16rne(u0.x); s[1] = (short)bf16rne(u0.y);
    s[2] = (short)bf16rne(u0.z); s[3] = (short)bf16rne(u0.w);
    s[4] = (short)bf16rne(u1.x); s[5] = (short)bf16rne(u1.y);
    s[6] = (short)bf16rne(u1.z); s[7] = (short)bf16rne(u1.w);
    const int g    = code >> 4;
    const int c16s = code & 15;
    const int half = j >> 2;
    const int qq   = j & 3;
    const size_t doff = (size_t)g * 1024 + half * 512 + (qq * 16 + c16s) * 8;
    *reinterpret_cast<short8*>(ebf + doff) = s;
}

// Main — WAVE-AUTONOMOUS register-staged single pass. r7 proved the floor
// is sync structure (halving barriers/blocks: -9.5us; work: ~0). This
// version removes ALL main-loop synchronization: each wave loads its own
// B-fragments global->VGPR (fragment-ordered ebf -> lane-contiguous,
// coalesced 1KB/instr), software-pipelined 2 chunks (2x2 tiles) deep in
// named register stages (static indices). No LDS staging, no dbuf, no
// __syncthreads between phase A and the epilogue (rows/cnt/clist are
// wave-private; compiler inserts counted vmcnt for the reg loads).
// dv bit-path (afr, b0/b1 bytes, 2-MFMA chain, fmaf(-2,acc,bn)) and the
// rolling-threshold collect cadence (4 tiles/round, prefix-min + W,
// MAXC=32) are IDENTICAL to the r3..r7 verified kernels; exact np rescore
// + lexic (s,k) unchanged; cnt>MAXC full-K fallback unchanged.
__global__ __launch_bounds__(256, 4)
void vq_main(const float* __restrict__ z, const float* __restrict__ emb,
             const unsigned short* __restrict__ ebf,
             const float* __restrict__ bn, float* __restrict__ out) {
    __shared__ float a_s[RPB];
    __shared__ float bn_s[KK];
    __shared__ int   cnt[RPB];
    __shared__ int   clist[RPB][MAXC];
    __shared__ int   bidx[RPB];
    __shared__ double lsum[4];

    const int tid  = threadIdx.x;
    const int lane = tid & 63;
    const int wv   = __builtin_amdgcn_readfirstlane(tid) >> 6;   // 0..3
    const int q    = lane >> 4;        // 0..3
    const int c16  = lane & 15;
    const int rowbase = blockIdx.x * RPB;

    // per-lane fragment base (fragment-ordered ebf): tile g's b0 frag for
    // this lane at g*2048 + lane*16, b1 at +1024.
    const char* ebase = (const char*)ebf + (size_t)lane * 16;

    // ---- phase A: exact row norms (8 lanes/row, r6-verified bit-path),
    //      bn_s stage, cnt zero ----
    {
        const int j8 = tid & 7;
#pragma unroll
        for (int sw = 0; sw < 2; ++sw) {
            const int rowl = 32 * sw + (tid >> 3);
            const float r = np_acc8(z + (size_t)(rowbase + rowl) * DD, j8);
            const float s1 = r  + __shfl_xor(r,  1, 64);
            const float s2 = s1 + __shfl_xor(s1, 2, 64);
            const float s3 = s2 + __shfl_xor(s2, 4, 64);
            if (j8 == 0) a_s[rowl] = s3;
        }
    }
    if (tid < RPB) cnt[tid] = 0;
    {
        const int i = tid * 4;
        *reinterpret_cast<float4*>(&bn_s[i]) =
            *reinterpret_cast<const float4*>(bn + i);
    }

    // ---- A-fragments (verified layout): rows 16wv+c16, k=32kh+8q+j ----
    short8 afr[2];
#pragma unroll
    for (int kh = 0; kh < 2; ++kh) {
        const float* zp = z + (size_t)(rowbase + 16 * wv + c16) * DD
                          + 32 * kh + 8 * q;
        const float4 u0 = *reinterpret_cast<const float4*>(zp);
        const float4 u1 = *reinterpret_cast<const float4*>(zp + 4);
        short8 s;
        s[0] = (short)bf16rne(u0.x); s[1] = (short)bf16rne(u0.y);
        s[2] = (short)bf16rne(u0.z); s[3] = (short)bf16rne(u0.w);
        s[4] = (short)bf16rne(u1.x); s[5] = (short)bf16rne(u1.y);
        s[6] = (short)bf16rne(u1.z); s[7] = (short)bf16rne(u1.w);
        afr[kh] = s;
    }

    __syncthreads();   // publish a_s / bn_s / cnt (ONLY pre-loop barrier)

    // W = 1.8e-4*||z|| + 1.2e-4 (verified window), per acc reg
    float wadd[4];
#pragma unroll
    for (int i = 0; i < 4; ++i) {
        const int rowl = 16 * wv + 4 * q + i;
        wadd[i] = 1.8e-4f * sqrtf(a_s[rowl]) + 1.2e-4f;
    }

    // chunk c = tiles {2c, 2c+1}; load its 4 b-frags + 2 bn values.
    auto loadChunk = [&](int c, short8 (&S)[4], float (&bnv)[2]) {
        const char* t0 = ebase + (size_t)c * 4096;          // tile 2c
        S[0] = *reinterpret_cast<const short8*>(t0);
        S[1] = *reinterpret_cast<const short8*>(t0 + 1024);
        S[2] = *reinterpret_cast<const short8*>(t0 + 2048); // tile 2c+1
        S[3] = *reinterpret_cast<const short8*>(t0 + 3072);
        bnv[0] = bn[32 * c + c16];
        bnv[1] = bn[32 * c + 16 + c16];
    };
    // compute chunk: 2 tiles -> dvt[0..1][4]  (bit-identical dv path)
    auto compute2 = [&](const short8 (&S)[4], const float (&bnv)[2],
                        float (*dvt)[4]) {
#pragma unroll
        for (int t = 0; t < 2; ++t) {
            f32x4 acc = {0.f, 0.f, 0.f, 0.f};
            acc = __builtin_amdgcn_mfma_f32_16x16x32_bf16(afr[0], S[2*t],   acc, 0, 0, 0);
            acc = __builtin_amdgcn_mfma_f32_16x16x32_bf16(afr[1], S[2*t+1], acc, 0, 0, 0);
#pragma unroll
            for (int r = 0; r < 4; ++r)
                dvt[t][r] = fmaf(-2.f, acc[r], bnv[t]);
        }
    };

    short8 SA[4], SB[4];
    float  bnA[2], bnB[2];
    loadChunk(0, SA, bnA);
    loadChunk(1, SB, bnB);

    float mn[4];
#pragma unroll
    for (int i = 0; i < 4; ++i) mn[i] = FLT_MAX;

    // ============ 16 rounds x 4 tiles (2 chunks), barrier-free ============
#pragma unroll 4
    for (int kp = 0; kp < 16; ++kp) {
        float dvt[4][4];
        compute2(SA, bnA, &dvt[0]);                 // tiles 4kp, 4kp+1
        if (kp < 15) loadChunk(2 * kp + 2, SA, bnA);
        compute2(SB, bnB, &dvt[2]);                 // tiles 4kp+2, 4kp+3
        if (kp < 15) loadChunk(2 * kp + 3, SB, bnB);

        // rolling per-lane min, then cross-lane min over 16 column-lanes
#pragma unroll
        for (int j = 0; j < 4; ++j)
#pragma unroll
            for (int r = 0; r < 4; ++r)
                mn[r] = fminf(mn[r], dvt[j][r]);
#pragma unroll
        for (int mask = 1; mask < 16; mask <<= 1)
#pragma unroll
            for (int r = 0; r < 4; ++r)
                mn[r] = fminf(mn[r], __shfl_xor(mn[r], mask, 64));
        float thr[4];
#pragma unroll
        for (int r = 0; r < 4; ++r) thr[r] = mn[r] + wadd[r];
        // collect (thr includes this round -> superset of final-min set)
#pragma unroll
        for (int j = 0; j < 4; ++j) {
            const int col = 16 * (4 * kp + j) + c16;
#pragma unroll
            for (int r = 0; r < 4; ++r) {
                if (dvt[j][r] <= thr[r]) {
                    const int rowl = 16 * wv + 4 * q + r;
                    const int slot = atomicAdd(&cnt[rowl], 1);
                    if (slot < MAXC) clist[rowl][slot] = col;
                }
            }
        }
    }

    // ---- rescore (verified): exact np chain, lexic (s,k) min.
    //      rows/cnt/clist are wave-private -> no barrier needed. ----
    {
        const int rowl = 16 * wv + c16;
        const int row  = rowbase + rowl;
        const int nc   = cnt[rowl];
        const bool full = nc > MAXC;    // overflow insurance
        const int lim  = full ? KK : nc;
        const float av = a_s[rowl];
        const float* zp = z + (size_t)row * DD;
        float sb = FLT_MAX;
        int   cb = 0x7fffffff;
        for (int jj = q; jj < lim; jj += 4) {
            const int c = full ? jj : clist[rowl][jj];
            const float* ep = emb + (size_t)c * DD;
            float dot = 0.f;
#pragma unroll
            for (int d = 0; d < DD; d += 4) {
                const float4 zv = *reinterpret_cast<const float4*>(zp + d);
                const float4 ev = *reinterpret_cast<const float4*>(ep + d);
                dot = fmaf(zv.x, ev.x, dot); dot = fmaf(zv.y, ev.y, dot);
                dot = fmaf(zv.z, ev.z, dot); dot = fmaf(zv.w, ev.w, dot);
            }
            const float tt = av + bn_s[c];
            const float sd = fmaf(-2.f, dot, tt);
            if (sd < sb || (sd == sb && c < cb)) { sb = sd; cb = c; }
        }
#pragma unroll
        for (int mask = 16; mask < 64; mask <<= 1) {
            const float so = __shfl_xor(sb, mask, 64);
            const int   co = __shfl_xor(cb, mask, 64);
            if (so < sb || (so == sb && co < cb)) { sb = so; cb = co; }
        }
        if (cb > 1023) cb = 0;   // safety: never OOB even if logic broke
        if (q == 0) bidx[rowl] = cb;
    }
    __syncthreads();   // publish bidx for the cross-wave epilogue mapping

    // ---- epilogue: 4 threads/row (64B each), coalesced (r6/r7-verified) ----
    {
        const int rowl = tid >> 2;        // 0..63
        const int sub  = tid & 3;         // owns floats sub*16..+15
        const int row  = rowbase + rowl;
        const int bid  = bidx[rowl];
        const float* ep = emb + (size_t)bid * DD + sub * 16;
        const float* zp = z + (size_t)row * DD + sub * 16;
        float* op = out + (size_t)row * DD + sub * 16;
        double sac = 0.0;
#pragma unroll
        for (int d = 0; d < 16; d += 4) {
            const float4 zv = *reinterpret_cast<const float4*>(zp + d);
            const float4 e4 = *reinterpret_cast<const float4*>(ep + d);
            const float df0 = e4.x - zv.x;
            const float df1 = e4.y - zv.y;
            const float df2 = e4.z - zv.z;
            const float df3 = e4.w - zv.w;
            float4 qv;
            qv.x = zv.x + df0; qv.y = zv.y + df1;
            qv.z = zv.z + df2; qv.w = zv.w + df3;
            *reinterpret_cast<float4*>(op + d) = qv;
            sac += (double)(df0 * df0); sac += (double)(df1 * df1);
            sac += (double)(df2 * df2); sac += (double)(df3 * df3);
        }
        if (sub == 0) out[IDX_OFF + row] = (float)bid;

        sac += __shfl_down(sac, 1, 64);
        sac += __shfl_down(sac, 2, 64);
        double v = (sub == 0) ? sac : 0.0;
#pragma unroll
        for (int off = 32; off > 0; off >>= 1) v += __shfl_down(v, off, 64);
        if (lane == 0) lsum[wv] = v;
    }
    __syncthreads();
    if (tid == 0)
        atomicAdd(&out[LOSS_OFF],
                  (float)((1.25 * (lsum[0] + lsum[1] + lsum[2] + lsum[3]))
                          / 262144.0));
}

extern "C" void kernel_launch(void* const* d_in, const int* in_sizes, int n_in,
                              void* d_out, int out_size, void* d_ws, size_t ws_size,
                              hipStream_t stream) {
    const float* z   = (const float*)d_in[0];   // [16,4096,64] fp32
    const float* emb = (const float*)d_in[1];   // [1024,64] fp32
    float* out = (float*)d_out;                 // zq | loss | idx (flat fp32)

    float*          bnw = (float*)d_ws;                          // 4 KB
    unsigned short* ebf = (unsigned short*)((char*)d_ws + 4096);  // 128 KB

    vq_prep<<<dim3(32), dim3(256), 0, stream>>>(emb, bnw, ebf);
    vq_main<<<dim3(NROWS / RPB), dim3(256), 0, stream>>>(z, emb, ebf, bnw, out);
}

// Round 11
// 116.737 us; speedup vs baseline: 1.0195x; 1.0195x over previous
//
#include <hip/hip_runtime.h>
#include <math.h>
#include <float.h>

// Problem constants (B=16, T=4096, D=64, K=1024)
#define NROWS    65536
#define DD       64
#define KK       1024
#define LOSS_OFF 4194304
#define IDX_OFF  4194305
#define RPB      128          // rows per block (8 waves x 16 rows)  [r7-verified]
#define MAXC     32           // candidate list capacity per row
#define TPR      8            // tiles per round (16 codes each, 1/wave)
#define NRND     8            // rounds (single pass)
#define NBLK     (NROWS / RPB)   // 512 blocks
#define WS_NEED  (4096 + 131072 + 4096)   // bn + ebf + psum

typedef short  short8 __attribute__((ext_vector_type(8)));   // 8 bf16
typedef float  f32x4  __attribute__((ext_vector_type(4)));

// Async global->LDS, 16B/lane (r10-verified; m97/m104 semantics).
__device__ __forceinline__ void async_copy16(void* lds, const void* g) {
    __builtin_amdgcn_global_load_lds(
        (const __attribute__((address_space(1))) unsigned int*)g,
        (__attribute__((address_space(3))) unsigned int*)lds, 16, 0, 0);
}

// float -> bf16 bits, RNE. Filter-side only.
__device__ __forceinline__ unsigned short bf16rne(float x) {
    unsigned int u = __float_as_uint(x);
    return (unsigned short)((u + 0x7fffu + ((u >> 16) & 1u)) >> 16);
}

// numpy strided accumulator r_j for n=64 pairwise sum (r6/r7-verified).
__device__ __forceinline__ float np_acc8(const float* p, int j) {
#pragma clang fp contract(off)
    float r = 0.f;
#pragma unroll
    for (int i = 0; i < 8; ++i) {
        const float v = p[8 * i + j];
        r += v * v;
    }
    return r;
}

// Prep (r5 layout, verified): norms bit-exact + fragment-ordered ebf:
// tile g stored as [1024B b0 frags in lane order][1024B b1 frags].
__global__ void vq_prep(const float* __restrict__ emb,
                        float* __restrict__ bn,
                        unsigned short* __restrict__ ebf) {
#pragma clang fp contract(off)
    const int gtid = blockIdx.x * 256 + threadIdx.x;   // 8192 threads
    const int code = gtid >> 3;
    const int j    = gtid & 7;
    const float* ep = emb + (size_t)code * DD;
    float r = 0.f;
#pragma unroll
    for (int i = 0; i < 8; ++i) {
        const float v = ep[8 * i + j];
        r += v * v;
    }
    const float s1 = r  + __shfl_xor(r,  1, 64);
    const float s2 = s1 + __shfl_xor(s1, 2, 64);
    const float s3 = s2 + __shfl_xor(s2, 4, 64);
    if (j == 0) bn[code] = s3;

    const float* cp = emb + (size_t)gtid * 8;
    const float4 u0 = *reinterpret_cast<const float4*>(cp);
    const float4 u1 = *reinterpret_cast<const float4*>(cp + 4);
    short8 s;
    s[0] = (short)bf16rne(u0.x); s[1] = (short)bf16rne(u0.y);
    s[2] = (short)bf16rne(u0.z); s[3] = (short)bf16rne(u0.w);
    s[4] = (short)bf16rne(u1.x); s[5] = (short)bf16rne(u1.y);
    s[6] = (short)bf16rne(u1.z); s[7] = (short)bf16rne(u1.w);
    const int g    = code >> 4;
    const int c16s = code & 15;
    const int half = j >> 2;
    const int qq   = j & 3;
    const size_t doff = (size_t)g * 1024 + half * 512 + (qq * 16 + c16s) * 8;
    *reinterpret_cast<short8*>(ebf + doff) = s;
}

// Main — r7 VERBATIM (53.9us, absmax 0.0) with the loss sink selectable:
// psum != nullptr -> store per-block f64 partial (contention-free; vq_fin
// reduces once). psum == nullptr -> r7's original single same-address
// atomicAdd per block (known-good fallback if workspace is too small).
__global__ __launch_bounds__(512, 4)
void vq_main(const float* __restrict__ z, const float* __restrict__ emb,
             const unsigned short* __restrict__ ebf,
             const float* __restrict__ bn, float* __restrict__ out,
             double* __restrict__ psum) {
    __shared__ char  dbuf[2][TPR * 2048] __attribute__((aligned(16)));  // 32 KB
    __shared__ float a_s[RPB];
    __shared__ float bn_s[KK];
    __shared__ int   cnt[RPB];
    __shared__ int   clist[RPB][MAXC];
    __shared__ int   bidx[RPB];
    __shared__ double lsum[8];

    const int tid  = threadIdx.x;
    const int lane = tid & 63;
    const int wv   = __builtin_amdgcn_readfirstlane(tid) >> 6;   // 0..7
    const int q    = lane >> 4;        // 0..3
    const int c16  = lane & 15;
    const int rowbase = blockIdx.x * RPB;

    // staging source: tile g at ebf + g*2048 bytes, lane reads its own 16B
    // at +lane*16 (b0 KB) and +1024+lane*16 (b1 KB) — contiguous, coalesced.
    const char* sbase = (const char*)ebf + (size_t)lane * 16;
    char* dst0 = &dbuf[0][wv * 2048 + lane * 16];
    char* dst1 = &dbuf[1][wv * 2048 + lane * 16];

    // ---- phase A: exact row norms, 8 lanes/row, all waves, 2 sweeps ----
    {
        const int j8 = tid & 7;
#pragma unroll
        for (int sw = 0; sw < 2; ++sw) {
            const int rowl = 64 * sw + (tid >> 3);   // 0..127
            const float r = np_acc8(z + (size_t)(rowbase + rowl) * DD, j8);
            const float s1 = r  + __shfl_xor(r,  1, 64);
            const float s2 = s1 + __shfl_xor(s1, 2, 64);
            const float s3 = s2 + __shfl_xor(s2, 4, 64);
            if (j8 == 0) a_s[rowl] = s3;
        }
    }
    if (tid < RPB) cnt[tid] = 0;
    {
        const int i = tid * 2;
        *reinterpret_cast<float2*>(&bn_s[i]) =
            *reinterpret_cast<const float2*>(bn + i);
    }

    // ---- A-fragments (verified layout): rows 16wv+c16, k=32kh+8q+j ----
    short8 afr[2];
#pragma unroll
    for (int kh = 0; kh < 2; ++kh) {
        const float* zp = z + (size_t)(rowbase + 16 * wv + c16) * DD
                          + 32 * kh + 8 * q;
        const float4 u0 = *reinterpret_cast<const float4*>(zp);
        const float4 u1 = *reinterpret_cast<const float4*>(zp + 4);
        short8 s;
        s[0] = (short)bf16rne(u0.x); s[1] = (short)bf16rne(u0.y);
        s[2] = (short)bf16rne(u0.z); s[3] = (short)bf16rne(u0.w);
        s[4] = (short)bf16rne(u1.x); s[5] = (short)bf16rne(u1.y);
        s[6] = (short)bf16rne(u1.z); s[7] = (short)bf16rne(u1.w);
        afr[kh] = s;
    }

    // wave stages tile (TPR*R + wv) of each round: 2 coalesced async copies
    auto stage = [&](int R, int buf) {
        const char* s0 = sbase + (size_t)(TPR * R + wv) * 2048;
        char* d = buf ? dst1 : dst0;
        async_copy16(d,        s0);
        async_copy16(d + 1024, s0 + 1024);
    };

    stage(0, 0);          // prologue (barrier also publishes phase-A LDS)
    __syncthreads();

    // W = 1.8e-4*||z|| + 1.2e-4 (verified window), per acc reg
    float wadd[4];
#pragma unroll
    for (int i = 0; i < 4; ++i) {
        const int rowl = 16 * wv + 4 * q + i;
        wadd[i] = 1.8e-4f * sqrtf(a_s[rowl]) + 1.2e-4f;
    }

    float mn[4];
#pragma unroll
    for (int i = 0; i < 4; ++i) mn[i] = FLT_MAX;

    // ============ single pass: 8 rounds x 8 tiles, rolling threshold ============
    for (int R = 0; R < NRND; ++R) {
        const int cur = R & 1;
        if (R < NRND - 1) stage(R + 1, cur ^ 1);
        float dv[TPR][4];
#pragma unroll
        for (int j = 0; j < TPR; ++j) {
            const char* tb = &dbuf[cur][j * 2048 + lane * 16];
            const short8 b0 = *reinterpret_cast<const short8*>(tb);
            const short8 b1 = *reinterpret_cast<const short8*>(tb + 1024);
            f32x4 acc = {0.f, 0.f, 0.f, 0.f};
            acc = __builtin_amdgcn_mfma_f32_16x16x32_bf16(afr[0], b0, acc, 0, 0, 0);
            acc = __builtin_amdgcn_mfma_f32_16x16x32_bf16(afr[1], b1, acc, 0, 0, 0);
            const float bnv = bn_s[16 * (TPR * R + j) + c16];
#pragma unroll
            for (int r = 0; r < 4; ++r)
                dv[j][r] = fmaf(-2.f, acc[r], bnv);
        }
        // rolling per-lane min, then cross-lane min over the 16 column-lanes
#pragma unroll
        for (int j = 0; j < TPR; ++j)
#pragma unroll
            for (int r = 0; r < 4; ++r)
                mn[r] = fminf(mn[r], dv[j][r]);
#pragma unroll
        for (int mask = 1; mask < 16; mask <<= 1)
#pragma unroll
            for (int r = 0; r < 4; ++r)
                mn[r] = fminf(mn[r], __shfl_xor(mn[r], mask, 64));
        float thr[4];
#pragma unroll
        for (int r = 0; r < 4; ++r) thr[r] = mn[r] + wadd[r];
        // collect (thr includes this round -> superset of final-min set)
#pragma unroll
        for (int j = 0; j < TPR; ++j) {
            const int col = 16 * (TPR * R + j) + c16;
#pragma unroll
            for (int r = 0; r < 4; ++r) {
                if (dv[j][r] <= thr[r]) {
                    const int rowl = 16 * wv + 4 * q + r;
                    const int slot = atomicAdd(&cnt[rowl], 1);
                    if (slot < MAXC) clist[rowl][slot] = col;
                }
            }
        }
        __syncthreads();   // publish next buffer (vmcnt drained), free cur
    }

    // ---- rescore (verified): exact np chain, lexic (s,k) min ----
    {
        const int rowl = 16 * wv + c16;
        const int row  = rowbase + rowl;
        const int nc   = cnt[rowl];     // rows are wave-private
        const bool full = nc > MAXC;    // overflow insurance
        const int lim  = full ? KK : nc;
        const float av = a_s[rowl];
        const float* zp = z + (size_t)row * DD;
        float sb = FLT_MAX;
        int   cb = 0x7fffffff;
        for (int jj = q; jj < lim; jj += 4) {
            const int c = full ? jj : clist[rowl][jj];
            const float* ep = emb + (size_t)c * DD;
            float dot = 0.f;
#pragma unroll
            for (int d = 0; d < DD; d += 4) {
                const float4 zv = *reinterpret_cast<const float4*>(zp + d);
                const float4 ev = *reinterpret_cast<const float4*>(ep + d);
                dot = fmaf(zv.x, ev.x, dot); dot = fmaf(zv.y, ev.y, dot);
                dot = fmaf(zv.z, ev.z, dot); dot = fmaf(zv.w, ev.w, dot);
            }
            const float tt = av + bn_s[c];
            const float sd = fmaf(-2.f, dot, tt);
            if (sd < sb || (sd == sb && c < cb)) { sb = sd; cb = c; }
        }
#pragma unroll
        for (int mask = 16; mask < 64; mask <<= 1) {
            const float so = __shfl_xor(sb, mask, 64);
            const int   co = __shfl_xor(cb, mask, 64);
            if (so < sb || (so == sb && co < cb)) { sb = so; cb = co; }
        }
        if (cb > 1023) cb = 0;   // safety: never OOB even if logic broke
        if (q == 0) bidx[rowl] = cb;
    }
    __syncthreads();

    // ---- epilogue: 4 threads/row (64B each), all waves, coalesced ----
    {
        const int rowl = tid >> 2;        // 0..127
        const int sub  = tid & 3;         // 0..3, owns floats sub*16..+15
        const int row  = rowbase + rowl;
        const int bid  = bidx[rowl];
        const float* ep = emb + (size_t)bid * DD + sub * 16;
        const float* zp = z + (size_t)row * DD + sub * 16;
        float* op = out + (size_t)row * DD + sub * 16;
        double sac = 0.0;
#pragma unroll
        for (int d = 0; d < 16; d += 4) {
            const float4 zv = *reinterpret_cast<const float4*>(zp + d);
            const float4 e4 = *reinterpret_cast<const float4*>(ep + d);
            const float df0 = e4.x - zv.x;
            const float df1 = e4.y - zv.y;
            const float df2 = e4.z - zv.z;
            const float df3 = e4.w - zv.w;
            float4 qv;
            qv.x = zv.x + df0; qv.y = zv.y + df1;
            qv.z = zv.z + df2; qv.w = zv.w + df3;
            *reinterpret_cast<float4*>(op + d) = qv;
            sac += (double)(df0 * df0); sac += (double)(df1 * df1);
            sac += (double)(df2 * df2); sac += (double)(df3 * df3);
        }
        if (sub == 0) out[IDX_OFF + row] = (float)bid;

        // combine 4 partials per row, then wave sum, then block partial.
        sac += __shfl_down(sac, 1, 64);
        sac += __shfl_down(sac, 2, 64);
        double v = (sub == 0) ? sac : 0.0;
#pragma unroll
        for (int off = 32; off > 0; off >>= 1) v += __shfl_down(v, off, 64);
        if (lane == 0) lsum[wv] = v;
    }
    __syncthreads();
    if (tid == 0) {
        double t = 0.0;
#pragma unroll
        for (int i = 0; i < 8; ++i) t += lsum[i];
        if (psum != nullptr)
            psum[blockIdx.x] = t;   // contention-free partial (vq_fin reduces)
        else
            atomicAdd(&out[LOSS_OFF], (float)((1.25 * t) / 262144.0));  // r7 path
    }
}

// Final reduce: one wave sums the 512 block partials and applies the loss
// once. Replaces 512 serialized same-address device-scope atomics.
__global__ void vq_fin(const double* __restrict__ psum,
                       float* __restrict__ out) {
    const int lane = threadIdx.x;      // 64 threads
    double t = 0.0;
#pragma unroll
    for (int i = 0; i < 8; ++i) t += psum[lane * 8 + i];
#pragma unroll
    for (int off = 32; off > 0; off >>= 1) t += __shfl_down(t, off, 64);
    if (lane == 0)
        atomicAdd(&out[LOSS_OFF], (float)((1.25 * t) / 262144.0));
}

extern "C" void kernel_launch(void* const* d_in, const int* in_sizes, int n_in,
                              void* d_out, int out_size, void* d_ws, size_t ws_size,
                              hipStream_t stream) {
    const float* z   = (const float*)d_in[0];   // [16,4096,64] fp32
    const float* emb = (const float*)d_in[1];   // [1024,64] fp32
    float* out = (float*)d_out;                 // zq | loss | idx (flat fp32)

    float*          bnw  = (float*)d_ws;                            // 4 KB
    unsigned short* ebf  = (unsigned short*)((char*)d_ws + 4096);   // 128 KB
    // psum only if the workspace provably fits it (guard against OOB writes
    // if ws_size is tight — r9/r10 failure audit).
    double* psum = (ws_size >= (size_t)WS_NEED)
                   ? (double*)((char*)d_ws + 4096 + 131072) : nullptr;

    vq_prep<<<dim3(32), dim3(256), 0, stream>>>(emb, bnw, ebf);
    vq_main<<<dim3(NBLK), dim3(512), 0, stream>>>(z, emb, ebf, bnw, out, psum);
    if (psum != nullptr)
        vq_fin<<<dim3(1), dim3(64), 0, stream>>>(psum, out);
}

// Round 12
// 115.097 us; speedup vs baseline: 1.0340x; 1.0142x over previous
//
#include <hip/hip_runtime.h>
#include <math.h>
#include <float.h>

// Problem constants (B=16, T=4096, D=64, K=1024)
#define NROWS    65536
#define DD       64
#define KK       1024
#define LOSS_OFF 4194304
#define IDX_OFF  4194305
#define RPB      128          // rows per block (8 waves x 16 rows)  [r7-verified]
#define MAXC     32           // candidate list capacity per row
#define TPR      8            // tiles per round (16 codes each, 1/wave)
#define NRND     8            // rounds (single pass)
#define NBLK     (NROWS / RPB)   // 512 blocks
#define WS_NEED  (4096 + 131072 + 4096)   // bn + ebf + psum

typedef short  short8 __attribute__((ext_vector_type(8)));   // 8 bf16
typedef float  f32x4  __attribute__((ext_vector_type(4)));

// Async global->LDS, 16B/lane (r10-verified; m97/m104 semantics).
__device__ __forceinline__ void async_copy16(void* lds, const void* g) {
    __builtin_amdgcn_global_load_lds(
        (const __attribute__((address_space(1))) unsigned int*)g,
        (__attribute__((address_space(3))) unsigned int*)lds, 16, 0, 0);
}

// float -> bf16 bits, RNE. Filter-side only.
__device__ __forceinline__ unsigned short bf16rne(float x) {
    unsigned int u = __float_as_uint(x);
    return (unsigned short)((u + 0x7fffu + ((u >> 16) & 1u)) >> 16);
}

// numpy strided accumulator r_j for n=64 pairwise sum (r6/r7-verified).
__device__ __forceinline__ float np_acc8(const float* p, int j) {
#pragma clang fp contract(off)
    float r = 0.f;
#pragma unroll
    for (int i = 0; i < 8; ++i) {
        const float v = p[8 * i + j];
        r += v * v;
    }
    return r;
}

// Prep (r5 layout, verified): norms bit-exact + fragment-ordered ebf:
// tile g stored as [1024B b0 frags in lane order][1024B b1 frags].
__global__ void vq_prep(const float* __restrict__ emb,
                        float* __restrict__ bn,
                        unsigned short* __restrict__ ebf) {
#pragma clang fp contract(off)
    const int gtid = blockIdx.x * 256 + threadIdx.x;   // 8192 threads
    const int code = gtid >> 3;
    const int j    = gtid & 7;
    const float* ep = emb + (size_t)code * DD;
    float r = 0.f;
#pragma unroll
    for (int i = 0; i < 8; ++i) {
        const float v = ep[8 * i + j];
        r += v * v;
    }
    const float s1 = r  + __shfl_xor(r,  1, 64);
    const float s2 = s1 + __shfl_xor(s1, 2, 64);
    const float s3 = s2 + __shfl_xor(s2, 4, 64);
    if (j == 0) bn[code] = s3;

    const float* cp = emb + (size_t)gtid * 8;
    const float4 u0 = *reinterpret_cast<const float4*>(cp);
    const float4 u1 = *reinterpret_cast<const float4*>(cp + 4);
    short8 s;
    s[0] = (short)bf16rne(u0.x); s[1] = (short)bf16rne(u0.y);
    s[2] = (short)bf16rne(u0.z); s[3] = (short)bf16rne(u0.w);
    s[4] = (short)bf16rne(u1.x); s[5] = (short)bf16rne(u1.y);
    s[6] = (short)bf16rne(u1.z); s[7] = (short)bf16rne(u1.w);
    const int g    = code >> 4;
    const int c16s = code & 15;
    const int half = j >> 2;
    const int qq   = j & 3;
    const size_t doff = (size_t)g * 1024 + half * 512 + (qq * 16 + c16s) * 8;
    *reinterpret_cast<short8*>(ebf + doff) = s;
}

// Main — r11's verified dataflow (absmax 0.0) with T3/T4 sync mechanics
// (m201 pattern): 3-buffer LDS rotation + counted vmcnt + raw s_barrier.
// Per round: stage(R+1)->buf[(R+1)%3]; vmcnt(2) (own stage(R) done, stage
// (R+1) stays in flight); s_barrier (all waves' stage(R) done -> buf[R%3]
// ready); sched_barrier(0); compute. No full vmcnt drains in the loop.
// Race analysis: barrier skew <= 1 round; stage(R+1) target differs from
// buf[R%3] (this round's reads) and buf[(R-1)%3] (laggard's reads) mod 3.
// Prologue: stage(0) issued before phase-A norms (DMA hides under L3
// latency); publish barrier is lgkmcnt-only so stage(0) isn't drained.
__global__ __launch_bounds__(512, 4)
void vq_main(const float* __restrict__ z, const float* __restrict__ emb,
             const unsigned short* __restrict__ ebf,
             const float* __restrict__ bn, float* __restrict__ out,
             double* __restrict__ psum) {
    __shared__ char  dbuf[3][TPR * 2048] __attribute__((aligned(16)));  // 48 KB
    __shared__ float a_s[RPB];
    __shared__ float bn_s[KK];
    __shared__ int   cnt[RPB];
    __shared__ int   clist[RPB][MAXC];
    __shared__ int   bidx[RPB];
    __shared__ double lsum[8];

    const int tid  = threadIdx.x;
    const int lane = tid & 63;
    const int wv   = __builtin_amdgcn_readfirstlane(tid) >> 6;   // 0..7
    const int q    = lane >> 4;        // 0..3
    const int c16  = lane & 15;
    const int rowbase = blockIdx.x * RPB;

    // staging source: tile g at ebf + g*2048 bytes, lane reads its own 16B
    // at +lane*16 (b0 KB) and +1024+lane*16 (b1 KB) — contiguous, coalesced.
    const char* sbase = (const char*)ebf + (size_t)lane * 16;

    // wave stages tile (TPR*R + wv) of round R into buffer b: 2 async copies
    auto stage = [&](int R, int b) {
        const char* s0 = sbase + (size_t)(TPR * R + wv) * 2048;
        char* d = &dbuf[b][wv * 2048 + lane * 16];
        async_copy16(d,        s0);
        async_copy16(d + 1024, s0 + 1024);
    };

    stage(0, 0);   // issue FIRST: DMA completes under phase-A latency

    // ---- phase A: exact row norms, 8 lanes/row, all waves, 2 sweeps ----
    {
        const int j8 = tid & 7;
#pragma unroll
        for (int sw = 0; sw < 2; ++sw) {
            const int rowl = 64 * sw + (tid >> 3);   // 0..127
            const float r = np_acc8(z + (size_t)(rowbase + rowl) * DD, j8);
            const float s1 = r  + __shfl_xor(r,  1, 64);
            const float s2 = s1 + __shfl_xor(s1, 2, 64);
            const float s3 = s2 + __shfl_xor(s2, 4, 64);
            if (j8 == 0) a_s[rowl] = s3;
        }
    }
    if (tid < RPB) cnt[tid] = 0;
    {
        const int i = tid * 2;
        *reinterpret_cast<float2*>(&bn_s[i]) =
            *reinterpret_cast<const float2*>(bn + i);
    }

    // ---- A-fragments (verified layout): rows 16wv+c16, k=32kh+8q+j ----
    short8 afr[2];
#pragma unroll
    for (int kh = 0; kh < 2; ++kh) {
        const float* zp = z + (size_t)(rowbase + 16 * wv + c16) * DD
                          + 32 * kh + 8 * q;
        const float4 u0 = *reinterpret_cast<const float4*>(zp);
        const float4 u1 = *reinterpret_cast<const float4*>(zp + 4);
        short8 s;
        s[0] = (short)bf16rne(u0.x); s[1] = (short)bf16rne(u0.y);
        s[2] = (short)bf16rne(u0.z); s[3] = (short)bf16rne(u0.w);
        s[4] = (short)bf16rne(u1.x); s[5] = (short)bf16rne(u1.y);
        s[6] = (short)bf16rne(u1.z); s[7] = (short)bf16rne(u1.w);
        afr[kh] = s;
    }

    // publish a_s / bn_s / cnt WITHOUT draining vmcnt (stage(0) stays live)
    asm volatile("s_waitcnt lgkmcnt(0)" ::: "memory");
    __builtin_amdgcn_s_barrier();
    __builtin_amdgcn_sched_barrier(0);

    // W = 1.8e-4*||z|| + 1.2e-4 (verified window), per acc reg
    float wadd[4];
#pragma unroll
    for (int i = 0; i < 4; ++i) {
        const int rowl = 16 * wv + 4 * q + i;
        wadd[i] = 1.8e-4f * sqrtf(a_s[rowl]) + 1.2e-4f;
    }

    float mn[4];
#pragma unroll
    for (int i = 0; i < 4; ++i) mn[i] = FLT_MAX;

    // ====== single pass: 8 rounds x 8 tiles, counted-vmcnt raw barriers ======
    for (int R = 0; R < NRND; ++R) {
        if (R < NRND - 1) {
            stage(R + 1, (R + 1) % 3);
            // own stage(R) done (oldest 2); stage(R+1)'s 2 stay in flight
            asm volatile("s_waitcnt vmcnt(2)" ::: "memory");
        } else {
            asm volatile("s_waitcnt vmcnt(0)" ::: "memory");
        }
        __builtin_amdgcn_s_barrier();       // all waves' stage(R) complete
        __builtin_amdgcn_sched_barrier(0);  // pin: no hoisting above barrier

        const char* base = dbuf[R % 3];
        float dv[TPR][4];
#pragma unroll
        for (int j = 0; j < TPR; ++j) {
            const char* tb = base + j * 2048 + lane * 16;
            const short8 b0 = *reinterpret_cast<const short8*>(tb);
            const short8 b1 = *reinterpret_cast<const short8*>(tb + 1024);
            f32x4 acc = {0.f, 0.f, 0.f, 0.f};
            acc = __builtin_amdgcn_mfma_f32_16x16x32_bf16(afr[0], b0, acc, 0, 0, 0);
            acc = __builtin_amdgcn_mfma_f32_16x16x32_bf16(afr[1], b1, acc, 0, 0, 0);
            const float bnv = bn_s[16 * (TPR * R + j) + c16];
#pragma unroll
            for (int r = 0; r < 4; ++r)
                dv[j][r] = fmaf(-2.f, acc[r], bnv);
        }
        // rolling per-lane min, then cross-lane min over the 16 column-lanes
#pragma unroll
        for (int j = 0; j < TPR; ++j)
#pragma unroll
            for (int r = 0; r < 4; ++r)
                mn[r] = fminf(mn[r], dv[j][r]);
#pragma unroll
        for (int mask = 1; mask < 16; mask <<= 1)
#pragma unroll
            for (int r = 0; r < 4; ++r)
                mn[r] = fminf(mn[r], __shfl_xor(mn[r], mask, 64));
        float thr[4];
#pragma unroll
        for (int r = 0; r < 4; ++r) thr[r] = mn[r] + wadd[r];
        // collect (thr includes this round -> superset of final-min set)
#pragma unroll
        for (int j = 0; j < TPR; ++j) {
            const int col = 16 * (TPR * R + j) + c16;
#pragma unroll
            for (int r = 0; r < 4; ++r) {
                if (dv[j][r] <= thr[r]) {
                    const int rowl = 16 * wv + 4 * q + r;
                    const int slot = atomicAdd(&cnt[rowl], 1);
                    if (slot < MAXC) clist[rowl][slot] = col;
                }
            }
        }
        // no trailing barrier: next round's top barrier is the rendezvous
    }
    __syncthreads();   // full drain once: publish cnt/clist for rescore

    // ---- rescore (verified): exact np chain, lexic (s,k) min ----
    {
        const int rowl = 16 * wv + c16;
        const int row  = rowbase + rowl;
        const int nc   = cnt[rowl];     // rows are wave-private
        const bool full = nc > MAXC;    // overflow insurance
        const int lim  = full ? KK : nc;
        const float av = a_s[rowl];
        const float* zp = z + (size_t)row * DD;
        float sb = FLT_MAX;
        int   cb = 0x7fffffff;
        for (int jj = q; jj < lim; jj += 4) {
            const int c = full ? jj : clist[rowl][jj];
            const float* ep = emb + (size_t)c * DD;
            float dot = 0.f;
#pragma unroll
            for (int d = 0; d < DD; d += 4) {
                const float4 zv = *reinterpret_cast<const float4*>(zp + d);
                const float4 ev = *reinterpret_cast<const float4*>(ep + d);
                dot = fmaf(zv.x, ev.x, dot); dot = fmaf(zv.y, ev.y, dot);
                dot = fmaf(zv.z, ev.z, dot); dot = fmaf(zv.w, ev.w, dot);
            }
            const float tt = av + bn_s[c];
            const float sd = fmaf(-2.f, dot, tt);
            if (sd < sb || (sd == sb && c < cb)) { sb = sd; cb = c; }
        }
#pragma unroll
        for (int mask = 16; mask < 64; mask <<= 1) {
            const float so = __shfl_xor(sb, mask, 64);
            const int   co = __shfl_xor(cb, mask, 64);
            if (so < sb || (so == sb && co < cb)) { sb = so; cb = co; }
        }
        if (cb > 1023) cb = 0;   // safety: never OOB even if logic broke
        if (q == 0) bidx[rowl] = cb;
    }
    __syncthreads();

    // ---- epilogue: 4 threads/row (64B each), all waves, coalesced ----
    {
        const int rowl = tid >> 2;        // 0..127
        const int sub  = tid & 3;         // 0..3, owns floats sub*16..+15
        const int row  = rowbase + rowl;
        const int bid  = bidx[rowl];
        const float* ep = emb + (size_t)bid * DD + sub * 16;
        const float* zp = z + (size_t)row * DD + sub * 16;
        float* op = out + (size_t)row * DD + sub * 16;
        double sac = 0.0;
#pragma unroll
        for (int d = 0; d < 16; d += 4) {
            const float4 zv = *reinterpret_cast<const float4*>(zp + d);
            const float4 e4 = *reinterpret_cast<const float4*>(ep + d);
            const float df0 = e4.x - zv.x;
            const float df1 = e4.y - zv.y;
            const float df2 = e4.z - zv.z;
            const float df3 = e4.w - zv.w;
            float4 qv;
            qv.x = zv.x + df0; qv.y = zv.y + df1;
            qv.z = zv.z + df2; qv.w = zv.w + df3;
            *reinterpret_cast<float4*>(op + d) = qv;
            sac += (double)(df0 * df0); sac += (double)(df1 * df1);
            sac += (double)(df2 * df2); sac += (double)(df3 * df3);
        }
        if (sub == 0) out[IDX_OFF + row] = (float)bid;

        // combine 4 partials per row, then wave sum, then block partial.
        sac += __shfl_down(sac, 1, 64);
        sac += __shfl_down(sac, 2, 64);
        double v = (sub == 0) ? sac : 0.0;
#pragma unroll
        for (int off = 32; off > 0; off >>= 1) v += __shfl_down(v, off, 64);
        if (lane == 0) lsum[wv] = v;
    }
    __syncthreads();
    if (tid == 0) {
        double t = 0.0;
#pragma unroll
        for (int i = 0; i < 8; ++i) t += lsum[i];
        if (psum != nullptr)
            psum[blockIdx.x] = t;   // contention-free partial (vq_fin reduces)
        else
            atomicAdd(&out[LOSS_OFF], (float)((1.25 * t) / 262144.0));
    }
}

// Final reduce: one wave sums the 512 block partials and applies the loss once.
__global__ void vq_fin(const double* __restrict__ psum,
                       float* __restrict__ out) {
    const int lane = threadIdx.x;      // 64 threads
    double t = 0.0;
#pragma unroll
    for (int i = 0; i < 8; ++i) t += psum[lane * 8 + i];
#pragma unroll
    for (int off = 32; off > 0; off >>= 1) t += __shfl_down(t, off, 64);
    if (lane == 0)
        atomicAdd(&out[LOSS_OFF], (float)((1.25 * t) / 262144.0));
}

extern "C" void kernel_launch(void* const* d_in, const int* in_sizes, int n_in,
                              void* d_out, int out_size, void* d_ws, size_t ws_size,
                              hipStream_t stream) {
    const float* z   = (const float*)d_in[0];   // [16,4096,64] fp32
    const float* emb = (const float*)d_in[1];   // [1024,64] fp32
    float* out = (float*)d_out;                 // zq | loss | idx (flat fp32)

    float*          bnw  = (float*)d_ws;                            // 4 KB
    unsigned short* ebf  = (unsigned short*)((char*)d_ws + 4096);   // 128 KB
    // psum only if the workspace provably fits it (r9/r10 failure audit).
    double* psum = (ws_size >= (size_t)WS_NEED)
                   ? (double*)((char*)d_ws + 4096 + 131072) : nullptr;

    vq_prep<<<dim3(32), dim3(256), 0, stream>>>(emb, bnw, ebf);
    vq_main<<<dim3(NBLK), dim3(512), 0, stream>>>(z, emb, ebf, bnw, out, psum);
    if (psum != nullptr)
        vq_fin<<<dim3(1), dim3(64), 0, stream>>>(psum, out);
}